// Round 1
// baseline (340.175 us; speedup 1.0000x reference)
//
#include <hip/hip_runtime.h>
#include <cstdint>
#include <cmath>

// ---------------------------------------------------------------------------
// MHKPattLayer fused kernel for MI355X (gfx950)
//   scores = einsum('bhtd,hnd->bhtn', q, key)        (3-pass bf16-split MFMA)
//   theta  = gelu_exact(scores * sqrt(N)/max(||row||2, 1e-8))
//   mask   = theta > mean(theta, row);  scores = theta * mask
//   out    = einsum('bhtn,hnv->bhtv', scores, val)   (bf16 MFMA)
// B=4, T=2048, C=1024, H=8, N=1024, Dk=Dv=128
// ---------------------------------------------------------------------------

typedef __bf16 bf16x8 __attribute__((ext_vector_type(8)));
typedef float  f32x16 __attribute__((ext_vector_type(16)));

__device__ __forceinline__ unsigned short f2bf(float f) {
  unsigned int u = __float_as_uint(f);
  unsigned int r = (u + 0x7FFFu + ((u >> 16) & 1u)) >> 16;  // RNE
  return (unsigned short)r;
}
__device__ __forceinline__ float bf2f(unsigned short b) {
  return __uint_as_float(((unsigned int)b) << 16);
}

// ---------------- prep kernels ----------------

// key_tokens fp32 -> bf16 hi + bf16 lo (residual), flat layout [H][N][Dk]
__global__ void prep_split_k(const float* __restrict__ src,
                             unsigned short* __restrict__ hi_o,
                             unsigned short* __restrict__ lo_o) {
  const int i = blockIdx.x * blockDim.x + threadIdx.x;  // 0..262143 (x4 floats)
  const float4 v = ((const float4*)src)[i];
  ushort4 hv, lv;
  {
    unsigned short hb;
    hb = f2bf(v.x); hv.x = hb; lv.x = f2bf(v.x - bf2f(hb));
    hb = f2bf(v.y); hv.y = hb; lv.y = f2bf(v.y - bf2f(hb));
    hb = f2bf(v.z); hv.z = hb; lv.z = f2bf(v.z - bf2f(hb));
    hb = f2bf(v.w); hv.w = hb; lv.w = f2bf(v.w - bf2f(hb));
  }
  ((ushort4*)hi_o)[i] = hv;
  ((ushort4*)lo_o)[i] = lv;
}

// val_tokens fp32 [H][N][Dv] -> bf16 transposed v_t [H][Dv][N]
__global__ void prep_vt(const float* __restrict__ val,
                        unsigned short* __restrict__ vt) {
  const int o = blockIdx.x * blockDim.x + threadIdx.x;  // 0..1048575
  const int hh  = o >> 17;
  const int rem = o & 131071;
  const int v   = rem >> 10;
  const int n   = rem & 1023;
  vt[o] = f2bf(val[(size_t)hh * 131072 + (size_t)n * 128 + v]);
}

// ---------------- fused kernel ----------------
// grid 1024 blocks (32 bh * 32 t-tiles), 512 threads (8 waves)
// LDS: S_bf16 [64][1032] (aliased with Q hi/lo staging [2][64][136]) + red[8][64]

#define QSTRIDE 136
#define QPART   (64 * 136)     // 8704 ushorts
#define SSTRIDE 1032
#define REDOFF  (64 * 1032 * 2)  // bytes
#define SMEMSZ  (REDOFF + 8 * 64 * 4)

__global__ __launch_bounds__(512, 2) void fused_mhk(
    const float* __restrict__ x,
    const unsigned short* __restrict__ k_hi,
    const unsigned short* __restrict__ k_lo,
    const unsigned short* __restrict__ v_t,
    float* __restrict__ out)
{
  extern __shared__ char smem[];
  unsigned short* q_lds = (unsigned short*)smem;   // [2][64][136] (phase 0/1 only)
  unsigned short* s_lds = (unsigned short*)smem;   // [64][1032]   (phase 3/4)
  float* red = (float*)(smem + REDOFF);            // [8][64]

  const int tid  = threadIdx.x;
  const int wave = tid >> 6;
  const int lane = tid & 63;
  const int l31  = lane & 31;
  const int hi   = lane >> 5;

  // block -> (bh, ttile): keep one head per XCD slot for L2 locality
  const int bid   = blockIdx.x;
  const int bh    = (bid & 7) * 4 + (bid >> 8);   // 0..31
  const int ttile = (bid >> 3) & 31;
  const int b     = bh >> 3;
  const int h     = bh & 7;
  const int t0    = ttile * 64;

  // ---- Phase 0: load Q tile [64][128] fp32, split -> bf16 hi/lo in LDS
  {
    const float* xq = x + ((size_t)b * 2048 + t0) * 1024 + h * 128;
    const int r  = tid >> 3;        // 0..63
    const int c0 = (tid & 7) * 16;  // 0,16,...,112
#pragma unroll
    for (int j = 0; j < 4; ++j) {
      const float4 v = *(const float4*)(xq + (size_t)r * 1024 + c0 + j * 4);
      ushort4 hv, lv;
      unsigned short hb;
      hb = f2bf(v.x); hv.x = hb; lv.x = f2bf(v.x - bf2f(hb));
      hb = f2bf(v.y); hv.y = hb; lv.y = f2bf(v.y - bf2f(hb));
      hb = f2bf(v.z); hv.z = hb; lv.z = f2bf(v.z - bf2f(hb));
      hb = f2bf(v.w); hv.w = hb; lv.w = f2bf(v.w - bf2f(hb));
      *(ushort4*)(q_lds + r * QSTRIDE + c0 + j * 4) = hv;
      *(ushort4*)(q_lds + QPART + r * QSTRIDE + c0 + j * 4) = lv;
    }
  }
  __syncthreads();

  // ---- Phase 1: QK^T swapped -> S^T[n][q]; lane holds q = l31 (+32*qt)
  // acc[t][qt]: n-tile t (n = wave*128 + t*32 + crow), q-tile qt
  f32x16 acc[4][2];
#pragma unroll
  for (int t = 0; t < 4; ++t)
#pragma unroll
    for (int q = 0; q < 2; ++q)
#pragma unroll
      for (int i = 0; i < 16; ++i) acc[t][q][i] = 0.f;

  const size_t krow = (size_t)h * 1024 * 128 +
                      (size_t)(wave * 128 + l31) * 128 + hi * 8;
#pragma unroll
  for (int s = 0; s < 8; ++s) {
    bf16x8 bq[2][2];  // [qt][hi/lo]  (B-operand = Q^T fragment)
#pragma unroll
    for (int qt = 0; qt < 2; ++qt) {
      const unsigned short* qp = q_lds + (qt * 32 + l31) * QSTRIDE + s * 16 + hi * 8;
      bq[qt][0] = *(const bf16x8*)(qp);
      bq[qt][1] = *(const bf16x8*)(qp + QPART);
    }
#pragma unroll
    for (int t = 0; t < 4; ++t) {
      const bf16x8 a_h = *(const bf16x8*)(k_hi + krow + t * 32 * 128 + s * 16);
      const bf16x8 a_l = *(const bf16x8*)(k_lo + krow + t * 32 * 128 + s * 16);
      acc[t][0] = __builtin_amdgcn_mfma_f32_32x32x16_bf16(a_h, bq[0][0], acc[t][0], 0, 0, 0);
      acc[t][1] = __builtin_amdgcn_mfma_f32_32x32x16_bf16(a_h, bq[1][0], acc[t][1], 0, 0, 0);
      acc[t][0] = __builtin_amdgcn_mfma_f32_32x32x16_bf16(a_h, bq[0][1], acc[t][0], 0, 0, 0);
      acc[t][1] = __builtin_amdgcn_mfma_f32_32x32x16_bf16(a_h, bq[1][1], acc[t][1], 0, 0, 0);
      acc[t][0] = __builtin_amdgcn_mfma_f32_32x32x16_bf16(a_l, bq[0][0], acc[t][0], 0, 0, 0);
      acc[t][1] = __builtin_amdgcn_mfma_f32_32x32x16_bf16(a_l, bq[1][0], acc[t][1], 0, 0, 0);
    }
  }

  // ---- Phase 2: row reductions (lane-local over n) + theta
  float ss0 = 0.f, ss1 = 0.f;
#pragma unroll
  for (int t = 0; t < 4; ++t)
#pragma unroll
    for (int r = 0; r < 16; ++r) {
      ss0 += acc[t][0][r] * acc[t][0][r];
      ss1 += acc[t][1][r] * acc[t][1][r];
    }
  ss0 += __shfl_xor(ss0, 32);
  ss1 += __shfl_xor(ss1, 32);
  if (lane < 32) {
    red[wave * 64 + lane]      = ss0;
    red[wave * 64 + 32 + lane] = ss1;
  }
  __syncthreads();
  float sum0 = 0.f, sum1 = 0.f;
#pragma unroll
  for (int w = 0; w < 8; ++w) {
    sum0 += red[w * 64 + l31];
    sum1 += red[w * 64 + 32 + l31];
  }
  const float scale0 = 32.f / fmaxf(sqrtf(sum0), 1e-8f);
  const float scale1 = 32.f / fmaxf(sqrtf(sum1), 1e-8f);
  __syncthreads();  // all reads of red[] complete before re-use

  float gs0 = 0.f, gs1 = 0.f;
#pragma unroll
  for (int t = 0; t < 4; ++t)
#pragma unroll
    for (int r = 0; r < 16; ++r) {
      float v0 = acc[t][0][r] * scale0;
      float g0 = 0.5f * v0 * (1.f + erff(v0 * 0.70710678f));
      acc[t][0][r] = g0; gs0 += g0;
      float v1 = acc[t][1][r] * scale1;
      float g1 = 0.5f * v1 * (1.f + erff(v1 * 0.70710678f));
      acc[t][1][r] = g1; gs1 += g1;
    }
  gs0 += __shfl_xor(gs0, 32);
  gs1 += __shfl_xor(gs1, 32);
  if (lane < 32) {
    red[wave * 64 + lane]      = gs0;
    red[wave * 64 + 32 + lane] = gs1;
  }
  __syncthreads();
  float m0 = 0.f, m1 = 0.f;
#pragma unroll
  for (int w = 0; w < 8; ++w) {
    m0 += red[w * 64 + l31];
    m1 += red[w * 64 + 32 + l31];
  }
  m0 *= (1.f / 1024.f);
  m1 *= (1.f / 1024.f);

  // ---- Phase 3: mask (strict >) + bf16 pack -> S in LDS [64 q][1032 n]
#pragma unroll
  for (int t = 0; t < 4; ++t) {
#pragma unroll
    for (int qt = 0; qt < 2; ++qt) {
      const float mn = qt ? m1 : m0;
#pragma unroll
      for (int rp = 0; rp < 8; ++rp) {
        const int r = rp * 2;
        float g0 = acc[t][qt][r];
        float g1 = acc[t][qt][r + 1];
        g0 = (g0 > mn) ? g0 : 0.f;
        g1 = (g1 > mn) ? g1 : 0.f;
        const unsigned int pk =
            (unsigned int)f2bf(g0) | ((unsigned int)f2bf(g1) << 16);
        const int n = wave * 128 + t * 32 + (r & 3) + 8 * (r >> 2) + 4 * hi;
        *(unsigned int*)(s_lds + (qt * 32 + l31) * SSTRIDE + n) = pk;
      }
    }
  }
  __syncthreads();

  // ---- Phase 4: PV. wave -> (qt = w>>2, vt = w&3) output tile 32x32, full n
  const int qt = wave >> 2;
  const int vt = wave & 3;
  f32x16 o;
#pragma unroll
  for (int i = 0; i < 16; ++i) o[i] = 0.f;

  const unsigned short* sp = s_lds + (qt * 32 + l31) * SSTRIDE + hi * 8;
  const unsigned short* vp = v_t + (size_t)h * 131072 +
                             (size_t)(vt * 32 + l31) * 1024 + hi * 8;
#pragma unroll 8
  for (int s = 0; s < 64; ++s) {
    const bf16x8 a  = *(const bf16x8*)(sp + s * 16);
    const bf16x8 bb = *(const bf16x8*)(vp + s * 16);
    o = __builtin_amdgcn_mfma_f32_32x32x16_bf16(a, bb, o, 0, 0, 0);
  }

  float* op = out + ((size_t)b * 2048 + t0 + qt * 32) * 1024 + h * 128 + vt * 32 + l31;
#pragma unroll
  for (int r = 0; r < 16; ++r) {
    const int q = (r & 3) + 8 * (r >> 2) + 4 * hi;
    op[(size_t)q * 1024] = o[r];
  }
}

// ---------------- launch ----------------

extern "C" void kernel_launch(void* const* d_in, const int* in_sizes, int n_in,
                              void* d_out, int out_size, void* d_ws, size_t ws_size,
                              hipStream_t stream) {
  const float* x   = (const float*)d_in[0];  // [4][2048][1024]
  const float* key = (const float*)d_in[1];  // [8][1024][128]
  const float* val = (const float*)d_in[2];  // [8][1024][128]
  float* out = (float*)d_out;                // [4][2048][1024]

  if (ws_size < (size_t)6 * 1024 * 1024) return;  // need 6 MB scratch

  unsigned short* k_hi = (unsigned short*)d_ws;   // 1M bf16
  unsigned short* k_lo = k_hi + 1048576;          // 1M bf16
  unsigned short* v_t  = k_lo + 1048576;          // 1M bf16 (transposed V)

  prep_split_k<<<dim3(1024), dim3(256), 0, stream>>>(key, k_hi, k_lo);
  prep_vt<<<dim3(4096), dim3(256), 0, stream>>>(val, v_t);
  fused_mhk<<<dim3(1024), dim3(512), SMEMSZ, stream>>>(x, k_hi, k_lo, v_t, out);
}

// Round 2
// 111.911 us; speedup vs baseline: 3.0397x; 3.0397x over previous
//
#include <hip/hip_runtime.h>
#include <cstdint>
#include <cmath>

// ---------------------------------------------------------------------------
// MHKPattLayer fused kernel for MI355X (gfx950) — round 2
//   QBLK=32, 8 waves, 2 blocks/CU. 3-pass bf16-split QK^T (exact-ish scores),
//   f32 l2norm+GELU+mean-mask in registers, bf16 PV.
// B=4, T=2048, C=1024, H=8, N=1024, Dk=Dv=128
// ---------------------------------------------------------------------------

typedef __bf16 bf16x8 __attribute__((ext_vector_type(8)));
typedef float  f32x16 __attribute__((ext_vector_type(16)));
typedef unsigned short u16x8 __attribute__((ext_vector_type(8)));

__device__ __forceinline__ unsigned short f2bf(float f) {
  unsigned int u = __float_as_uint(f);
  unsigned int r = (u + 0x7FFFu + ((u >> 16) & 1u)) >> 16;  // RNE
  return (unsigned short)r;
}
__device__ __forceinline__ float bf2f(unsigned short b) {
  return __uint_as_float(((unsigned int)b) << 16);
}

// exact GELU via A&S 7.1.26 erf (|eps| <= 1.5e-7), branchless
__device__ __forceinline__ float gelu_exact(float v) {
  const float s = v * 0.70710678118654752f;
  const float a = fabsf(s);
  const float t = __builtin_amdgcn_rcpf(fmaf(0.3275911f, a, 1.0f));
  float p = fmaf(1.061405429f, t, -1.453152027f);
  p = fmaf(p, t, 1.421413741f);
  p = fmaf(p, t, -0.284496736f);
  p = fmaf(p, t, 0.254829592f);
  p *= t;
  const float e = __expf(-a * a);
  float er = fmaf(-p, e, 1.0f);
  er = copysignf(er, s);
  return 0.5f * v * (1.0f + er);
}

// ---------------- prep kernels ----------------
// K (fp32 [8][1024][128]) -> hi/lo bf16 fragment-packed: [h][s2=16][n=1024][e=8]
// element = key[h][n][s2*8+e]; a wave's MFMA A-frag load is then contiguous.
__global__ void prep_k(const float* __restrict__ key,
                       unsigned short* __restrict__ kh,
                       unsigned short* __restrict__ kl) {
  const int tid = blockIdx.x * 256 + threadIdx.x;   // 0..131071
  const int h   = tid >> 14;
  const int s2  = (tid >> 10) & 15;
  const int n   = tid & 1023;
  const float* src = key + ((size_t)(h << 10) + n) * 128 + s2 * 8;
  const float4 f0 = *(const float4*)src;
  const float4 f1 = *(const float4*)(src + 4);
  const float fv[8] = {f0.x, f0.y, f0.z, f0.w, f1.x, f1.y, f1.z, f1.w};
  u16x8 hv, lv;
#pragma unroll
  for (int e = 0; e < 8; ++e) {
    const unsigned short hb = f2bf(fv[e]);
    hv[e] = hb;
    lv[e] = f2bf(fv[e] - bf2f(hb));
  }
  const size_t o = ((size_t)(h * 16 + s2) * 1024 + n) * 8;
  *(u16x8*)(kh + o) = hv;
  *(u16x8*)(kl + o) = lv;
}

// V (fp32 [8][1024][128]) -> bf16 fragment-packed: [h][s2=128][v=128][e=8]
// element = val[h][s2*8+e][v]; PV B-frag load is contiguous 16B/lane.
__global__ void prep_v(const float* __restrict__ val,
                       unsigned short* __restrict__ vp) {
  const int tid = blockIdx.x * 256 + threadIdx.x;   // 0..131071
  const int h   = tid >> 14;
  const int s2  = (tid >> 7) & 127;
  const int v   = tid & 127;
  const float* src = val + ((size_t)(h << 10) + s2 * 8) * 128 + v;
  u16x8 ov;
#pragma unroll
  for (int e = 0; e < 8; ++e) ov[e] = f2bf(src[(size_t)e * 128]);
  *(u16x8*)(vp + ((size_t)(h * 128 + s2) * 128 + v) * 8) = ov;
}

// ---------------- fused kernel ----------------
// grid 2048 (h = bid&7 -> one head per XCD), 512 threads (8 waves)
// LDS: S bf16 [32][1024] swizzled (64KB, aliases Q staging 16KB) + 2x red (2KB)
#define RED1   65536
#define RED2   66560
#define SMEMSZ 67584

__global__ __launch_bounds__(512, 4) void fused_mhk(
    const float* __restrict__ x,
    const unsigned short* __restrict__ k_hi,
    const unsigned short* __restrict__ k_lo,
    const unsigned short* __restrict__ v_pk,
    float* __restrict__ out)
{
  extern __shared__ char smem[];
  const int tid  = threadIdx.x;
  const int wave = tid >> 6;
  const int lane = tid & 63;
  const int l31  = lane & 31;
  const int hi   = lane >> 5;

  const int bid = blockIdx.x;
  const int h   = bid & 7;          // head fixed per XCD slot
  const int b   = (bid >> 3) & 3;
  const int tt  = bid >> 5;         // 0..63
  const int t0  = tt * 32;

  // ---- Phase 0: load Q tile [32][128] fp32, split -> bf16 hi/lo in LDS
  // Q layout: row*256B + (colbyte ^ ((row&15)<<4)); hi at 0, lo at +8192
  {
    const float* xq = x + ((size_t)(b * 2048 + t0)) * 1024 + h * 128;
    const int r  = tid >> 4;        // 0..31
    const int ci = tid & 15;        // 16B chunk
    const float* sp = xq + (size_t)r * 1024 + ci * 8;
    const float4 f0 = *(const float4*)sp;
    const float4 f1 = *(const float4*)(sp + 4);
    const float fv[8] = {f0.x, f0.y, f0.z, f0.w, f1.x, f1.y, f1.z, f1.w};
    u16x8 hv, lv;
#pragma unroll
    for (int e = 0; e < 8; ++e) {
      const unsigned short hb = f2bf(fv[e]);
      hv[e] = hb;
      lv[e] = f2bf(fv[e] - bf2f(hb));
    }
    const int cb = (ci * 16) ^ ((r & 15) << 4);
    *(u16x8*)(smem + r * 256 + cb) = hv;
    *(u16x8*)(smem + 8192 + r * 256 + cb) = lv;
  }
  __syncthreads();

  // ---- Phase 1: swapped QK^T -> S^T fragments; lane holds q = l31
  // acc[t]: n = wave*128 + t*32 + crow(r,hi)
  f32x16 acc[4];
#pragma unroll
  for (int t = 0; t < 4; ++t)
#pragma unroll
    for (int i = 0; i < 16; ++i) acc[t][i] = 0.f;

  {
    const unsigned short* khh = k_hi + (size_t)h * 131072;
    const unsigned short* khl = k_lo + (size_t)h * 131072;
    const int qoff = (l31 & 15) << 4;
#pragma unroll
    for (int s = 0; s < 8; ++s) {
      const int cb = ((32 * s + 16 * hi) ^ qoff) + l31 * 256;
      const bf16x8 bqh = *(const bf16x8*)(smem + cb);
      const bf16x8 bql = *(const bf16x8*)(smem + 8192 + cb);
      const size_t kbase = (size_t)(s * 2 + hi) * 8192 +
                           (size_t)(wave * 128 + l31) * 8;
#pragma unroll
      for (int t = 0; t < 4; ++t) {
        const bf16x8 ah = *(const bf16x8*)(khh + kbase + t * 256);
        const bf16x8 al = *(const bf16x8*)(khl + kbase + t * 256);
        acc[t] = __builtin_amdgcn_mfma_f32_32x32x16_bf16(ah, bqh, acc[t], 0, 0, 0);
        acc[t] = __builtin_amdgcn_mfma_f32_32x32x16_bf16(ah, bql, acc[t], 0, 0, 0);
        acc[t] = __builtin_amdgcn_mfma_f32_32x32x16_bf16(al, bqh, acc[t], 0, 0, 0);
      }
    }
  }

  // ---- Phase 2: l2-norm -> scale -> GELU -> mean (per q-row = per lane l31)
  float* red1 = (float*)(smem + RED1);
  float* red2 = (float*)(smem + RED2);

  float ss = 0.f;
#pragma unroll
  for (int t = 0; t < 4; ++t)
#pragma unroll
    for (int i = 0; i < 16; ++i) ss += acc[t][i] * acc[t][i];
  ss += __shfl_xor(ss, 32);
  if (lane < 32) red1[wave * 32 + lane] = ss;
  __syncthreads();
  float sum = 0.f;
#pragma unroll
  for (int w = 0; w < 8; ++w) sum += red1[w * 32 + l31];
  const float scale = 32.0f / fmaxf(sqrtf(sum), 1e-8f);

  float gs = 0.f;
#pragma unroll
  for (int t = 0; t < 4; ++t)
#pragma unroll
    for (int i = 0; i < 16; ++i) {
      const float g = gelu_exact(acc[t][i] * scale);
      acc[t][i] = g;
      gs += g;
    }
  gs += __shfl_xor(gs, 32);
  if (lane < 32) red2[wave * 32 + lane] = gs;
  __syncthreads();
  float mean = 0.f;
#pragma unroll
  for (int w = 0; w < 8; ++w) mean += red2[w * 32 + l31];
  mean *= (1.0f / 1024.0f);

  // ---- Phase 3: mask + pack bf16 -> S LDS [q=32][n=1024] XOR-swizzled
  // byte = q*2048 + (2n ^ ((q&31)<<4))
  {
    const int swz  = (l31 & 31) << 4;
    const int rowb = l31 * 2048;
#pragma unroll
    for (int t = 0; t < 4; ++t) {
#pragma unroll
      for (int g = 0; g < 4; ++g) {
        float g0 = acc[t][4 * g + 0]; g0 = (g0 > mean) ? g0 : 0.f;
        float g1 = acc[t][4 * g + 1]; g1 = (g1 > mean) ? g1 : 0.f;
        float g2 = acc[t][4 * g + 2]; g2 = (g2 > mean) ? g2 : 0.f;
        float g3 = acc[t][4 * g + 3]; g3 = (g3 > mean) ? g3 : 0.f;
        const unsigned int u0 = (unsigned)f2bf(g0) | ((unsigned)f2bf(g1) << 16);
        const unsigned int u1 = (unsigned)f2bf(g2) | ((unsigned)f2bf(g3) << 16);
        // n = wave*128 + t*32 + 4*hi + 8*g + {0..3}; colbyte = 2n
        const int cb = (wave * 256 + t * 64 + 8 * hi + 16 * g) ^ swz;
        *(uint2*)(smem + rowb + cb) = make_uint2(u0, u1);
      }
    }
  }
  __syncthreads();

  // ---- Phase 4: PV. waves 0..3 only; vt = wave; full n sweep
  if (wave >= 4) return;
  const int vt = wave;
  f32x16 o;
#pragma unroll
  for (int i = 0; i < 16; ++i) o[i] = 0.f;

  const unsigned short* vp = v_pk + (size_t)h * 131072 + (size_t)hi * 1024 +
                             (size_t)(vt * 32 + l31) * 8;
  const int swz  = (l31 & 31) << 4;
  const int rowb = l31 * 2048;
#pragma unroll 8
  for (int s = 0; s < 64; ++s) {
    const bf16x8 aa = *(const bf16x8*)(smem + rowb + ((32 * s + 16 * hi) ^ swz));
    const bf16x8 bb = *(const bf16x8*)(vp + (size_t)s * 2048);
    o = __builtin_amdgcn_mfma_f32_32x32x16_bf16(aa, bb, o, 0, 0, 0);
  }

  float* op = out + ((size_t)(b * 2048 + t0)) * 1024 + h * 128 + vt * 32 + l31;
#pragma unroll
  for (int r = 0; r < 16; ++r) {
    const int q = (r & 3) + 8 * (r >> 2) + 4 * hi;
    op[(size_t)q * 1024] = o[r];
  }
}

// ---------------- launch ----------------

extern "C" void kernel_launch(void* const* d_in, const int* in_sizes, int n_in,
                              void* d_out, int out_size, void* d_ws, size_t ws_size,
                              hipStream_t stream) {
  const float* x   = (const float*)d_in[0];  // [4][2048][1024]
  const float* key = (const float*)d_in[1];  // [8][1024][128]
  const float* val = (const float*)d_in[2];  // [8][1024][128]
  float* out = (float*)d_out;                // [4][2048][1024]

  if (ws_size < (size_t)6 * 1024 * 1024) return;  // need 6 MB scratch

  unsigned short* k_hi = (unsigned short*)d_ws;   // 1M bf16 (2 MB)
  unsigned short* k_lo = k_hi + 1048576;          // 1M bf16
  unsigned short* v_pk = k_lo + 1048576;          // 1M bf16 (frag-packed V)

  prep_k<<<dim3(512), dim3(256), 0, stream>>>(key, k_hi, k_lo);
  prep_v<<<dim3(512), dim3(256), 0, stream>>>(val, v_pk);
  fused_mhk<<<dim3(2048), dim3(512), SMEMSZ, stream>>>(x, k_hi, k_lo, v_pk, out);
}